// Round 2
// baseline (260.992 us; speedup 1.0000x reference)
//
#include <hip/hip_runtime.h>
#include <hip/hip_bf16.h>

#define IDIM  256
#define GDIM  64
#define ODIM  512
#define KD    (IDIM * GDIM)

typedef __attribute__((ext_vector_type(8))) short bhalf8;
typedef __attribute__((ext_vector_type(4))) float fvec4;

#define INV2PI 0.15915494309189535f

static __device__ __forceinline__ short bf16b(float v) {
    __hip_bfloat16 hb = __float2bfloat16(v);
    short s; __builtin_memcpy(&s, &hb, 2); return s;
}

// K-structure: step s in [0,64): i = i0 + (s>>1), trig = (s&1)?sin:cos.
// Each step is a 64-wide K-slice (g=1..64) fed to 16x16x32 bf16 MFMA.
// A-tile 256x64 bf16 (trig, computed in-reg via Chebyshev recurrence),
// B-tile 256x64 bf16 (coeffs f32->bf16), both XOR-swizzled (^(row&7)<<4),
// double-buffered: 4 x 32KB = 128KB LDS.
__global__ void __launch_bounds__(512, 2)
fkan_gemm(const float* __restrict__ x, const float* __restrict__ coeffs,
          float* __restrict__ out) {
    __shared__ __align__(16) short A_lds[2][256 * 64];
    __shared__ __align__(16) short B_lds[2][256 * 64];

    const int bx = blockIdx.x;
    const int xcd = bx & 7, jj = bx >> 3;
    const int lg = xcd * 2 + (jj & 1);   // (ot,ks) groups pinned per-XCD for B L2 reuse
    const int mt = jj >> 1;
    const int ot = lg >> 3, ks = lg & 7;
    const int row0 = mt * 256, col0 = ot * 256;
    const int i0 = ks * 32;

    const int t = threadIdx.x;
    const int lane = t & 63, wid = t >> 6;
    const int wave_m = wid & 1, wave_n = wid >> 1;

    const int ar = t >> 1;     // A-stage row 0..255
    const int h  = t & 1;      // A-stage k-half (k in [32h+1, 32h+32])
    const int bo = t >> 1;     // B-stage o-row
    const int bh = t & 1;      // B-stage g-half

    const float* xp  = x + (size_t)(row0 + ar) * IDIM + i0;
    const float* cb0 = coeffs + (size_t)(col0 + bo) * KD + (size_t)bh * 32 + (size_t)i0 * 64;
    const float* cb1 = cb0 + (size_t)ODIM * KD;

    const int rAb = wave_m * 128 + (lane & 15);
    const int rBb = wave_n * 64 + (lane & 15);
    const int kl  = (lane >> 4) * 16;
    const int msk = (lane & 7) << 4;

    fvec4 acc[8][4];
#pragma unroll
    for (int a = 0; a < 8; ++a)
#pragma unroll
        for (int b = 0; b < 4; ++b) acc[a][b] = (fvec4)0.0f;

    bhalf8 cpk4[4], spk4[4];   // cos/sin packs for one i (32 k-values each)
    fvec4 breg[8];             // in-flight B prefetch (32 f32)

    // Chebyshev: T_{k+1} = 2cos(x) T_k - T_{k-1}, same coeff for cos & sin chains.
    auto trig_chain = [&](float xv) {
        float rev = xv * INV2PI;
        float a1 = __builtin_amdgcn_fractf(rev);
        float c1 = __builtin_amdgcn_cosf(a1);
        float s1 = __builtin_amdgcn_sinf(a1);
        float C2 = 2.0f * c1;
        float cA, sA, cB, sB;                 // T_{k0}, T_{k0+1}
        if (h == 0) { cA = 1.0f; sA = 0.0f; cB = c1; sB = s1; }
        else {
            float a32 = __builtin_amdgcn_fractf(rev * 32.0f);
            float c32 = __builtin_amdgcn_cosf(a32);
            float s32 = __builtin_amdgcn_sinf(a32);
            cA = c32; sA = s32;
            cB = c1 * c32 - s1 * s32;         // cos(33x)
            sB = s1 * c32 + c1 * s32;         // sin(33x)
        }
#pragma unroll
        for (int p = 0; p < 4; ++p) {
            bhalf8 cpk, spk;
#pragma unroll
            for (int u = 0; u < 8; ++u) {
                cpk[u] = bf16b(cB); spk[u] = bf16b(sB);
                float cn = __builtin_fmaf(C2, cB, -cA);
                float sn = __builtin_fmaf(C2, sB, -sA);
                cA = cB; cB = cn; sA = sB; sB = sn;
            }
            cpk4[p] = cpk; spk4[p] = spk;
        }
    };

    auto writeA = [&](short* Ab, const bhalf8* cp) {
#pragma unroll
        for (int p = 0; p < 4; ++p)
            *(bhalf8*)((char*)Ab + (size_t)ar * 128 +
                       (((32 * h + 8 * p) * 2) ^ ((ar & 7) << 4))) = cp[p];
    };

    auto issueB = [&](int s1) {
        const fvec4* q = (const fvec4*)(((s1 & 1) ? cb1 : cb0) + (size_t)(s1 >> 1) * 64);
#pragma unroll
        for (int m = 0; m < 8; ++m) breg[m] = q[m];
    };

    auto writeB = [&](short* Bb) {
#pragma unroll
        for (int j2 = 0; j2 < 4; ++j2) {
            bhalf8 pk;
#pragma unroll
            for (int u = 0; u < 8; ++u) pk[u] = bf16b(breg[j2 * 2 + (u >> 2)][u & 3]);
            *(bhalf8*)((char*)Bb + (size_t)bo * 128 +
                       ((bh * 64 + j2 * 16) ^ ((bo & 7) << 4))) = pk;
        }
    };

    auto dsA = [&](bhalf8* af, const short* Ab, int hm) {
#pragma unroll
        for (int fm = 0; fm < 4; ++fm)
#pragma unroll
            for (int k2 = 0; k2 < 2; ++k2)
                af[fm * 2 + k2] = *(const bhalf8*)((const char*)Ab +
                    (size_t)(rAb + hm * 64 + fm * 16) * 128 + ((k2 * 64 + kl) ^ msk));
    };
    auto dsB = [&](bhalf8* bq, const short* Bb, int hn) {
#pragma unroll
        for (int fn = 0; fn < 2; ++fn)
#pragma unroll
            for (int k2 = 0; k2 < 2; ++k2)
                bq[fn * 2 + k2] = *(const bhalf8*)((const char*)Bb +
                    (size_t)(rBb + hn * 32 + fn * 16) * 128 + ((k2 * 64 + kl) ^ msk));
    };
    auto quad = [&](const bhalf8* af, const bhalf8* bq, int hm, int hn) {
#pragma unroll
        for (int k2 = 0; k2 < 2; ++k2)
#pragma unroll
            for (int fm = 0; fm < 4; ++fm)
#pragma unroll
                for (int fn = 0; fn < 2; ++fn)
                    acc[hm * 4 + fm][hn * 2 + fn] = __builtin_amdgcn_mfma_f32_16x16x32_bf16(
                        af[fm * 2 + k2], bq[fn * 2 + k2], acc[hm * 4 + fm][hn * 2 + fn], 0, 0, 0);
    };

    // ---- prologue: stage step 0 (cos, i0); stash sin packs for step 1 ----
    issueB(0);
    float xcur = xp[0];
    float xnext = xp[1];
    trig_chain(xcur);
    writeA((short*)A_lds[0], cpk4);
    writeB((short*)B_lds[0]);
    __syncthreads();

    bhalf8 af[8], bq[4];
#pragma unroll 1
    for (int s = 0; s < 64; ++s) {
        const short* Ac = A_lds[s & 1];
        const short* Bc = B_lds[s & 1];
        short* An = (short*)A_lds[(s & 1) ^ 1];
        short* Bn = (short*)B_lds[(s & 1) ^ 1];
        const bool last = (s == 63);
        const bool oddS = (s & 1) != 0;

        // P0: issue next-step B loads (in flight until P3); MFMA (hm0,hn0)
        if (!last) issueB(s + 1);
        dsA(af, Ac, 0);
        dsB(bq, Bc, 0);
        __builtin_amdgcn_s_barrier();
        __builtin_amdgcn_s_setprio(1);
        quad(af, bq, 0, 0);
        __builtin_amdgcn_s_setprio(0);

        // P1: trig recurrence for next i (odd steps only); MFMA (hm0,hn1)
        if (!last && oddS) trig_chain(xnext);
        dsB(bq, Bc, 1);
        __builtin_amdgcn_s_barrier();
        __builtin_amdgcn_s_setprio(1);
        quad(af, bq, 0, 1);
        __builtin_amdgcn_s_setprio(0);

        // P2: write A packs for next step (odd: fresh cos; even: stashed sin); MFMA (hm1,hn1)
        if (!last) writeA(An, oddS ? cpk4 : spk4);
        dsA(af, Ac, 1);
        __builtin_amdgcn_s_barrier();
        __builtin_amdgcn_s_setprio(1);
        quad(af, bq, 1, 1);
        __builtin_amdgcn_s_setprio(0);

        // P3: cvt+write B (waits its vmcnt here, 3 phases in flight);
        //     publish LDS writes (the ONLY memory barrier per step); MFMA (hm1,hn0)
        if (!last) writeB(Bn);
        if (!last && oddS && s <= 59) xnext = xp[(s >> 1) + 2];
        dsB(bq, Bc, 0);
        asm volatile("s_waitcnt lgkmcnt(0)" ::: "memory");
        __builtin_amdgcn_s_barrier();
        __builtin_amdgcn_s_setprio(1);
        quad(af, bq, 1, 0);
        __builtin_amdgcn_s_setprio(0);
    }

    // epilogue: C/D layout col=lane&15, row=(lane>>4)*4+r
#pragma unroll
    for (int fm = 0; fm < 8; ++fm) {
#pragma unroll
        for (int fn = 0; fn < 4; ++fn) {
            int col = col0 + wave_n * 64 + fn * 16 + (lane & 15);
#pragma unroll
            for (int r = 0; r < 4; ++r) {
                int row = row0 + wave_m * 128 + fm * 16 + ((lane >> 4) * 4) + r;
                atomicAdd(&out[(size_t)row * ODIM + col], acc[fm][fn][r]);
            }
        }
    }
}

__global__ void bias_init(const float* __restrict__ bias, float* __restrict__ out) {
    int idx = blockIdx.x * 256 + threadIdx.x;          // over 2M/4 f32x4
    fvec4 bv = ((const fvec4*)bias)[idx & 127];        // 128 f32x4 per output row
    ((fvec4*)out)[idx] = bv;
}

extern "C" void kernel_launch(void* const* d_in, const int* in_sizes, int n_in,
                              void* d_out, int out_size, void* d_ws, size_t ws_size,
                              hipStream_t stream) {
    (void)in_sizes; (void)n_in; (void)d_ws; (void)ws_size; (void)out_size;
    const float* x      = (const float*)d_in[0];
    const float* coeffs = (const float*)d_in[1];
    const float* bias   = (const float*)d_in[2];
    float* out = (float*)d_out;

    bias_init<<<dim3(2048), dim3(256), 0, stream>>>(bias, out);
    fkan_gemm<<<dim3(256), dim3(512), 0, stream>>>(x, coeffs, out);
}